// Round 3
// baseline (68.867 us; speedup 1.0000x reference)
//
#include <hip/hip_runtime.h>
#include <math.h>

#define NEGV (-1.0e9f)
#define HPAD 65

__device__ __forceinline__ float clip1000(float v) {
  return fminf(fmaxf(v, -1000.0f), 1000.0f);
}

__launch_bounds__(1024, 1)
__global__ void sim_kernel(const int* __restrict__ tables,
                           const int* __restrict__ sigma,
                           const int* __restrict__ x,
                           const int* __restrict__ base_obs,
                           const float* __restrict__ W1,
                           const float* __restrict__ b1,
                           const float* __restrict__ W2,
                           const float* __restrict__ b2,
                           const int* __restrict__ max_steps_p,
                           float* __restrict__ out,
                           int B, int V, int N)
{
  const int b = blockIdx.x;
  const int tid = threadIdx.x;
  const int T = max_steps_p[0];

  __shared__ int s_idx[2][8192];      // candidate index lists (ping-pong)
  __shared__ int s_surv[256];         // survival flags for fast fused pass
  __shared__ int s_hist[32 * HPAD];   // padded: kills stride-64 bank conflicts
  __shared__ float s_z[33];
  __shared__ int s_used[32];
  __shared__ int s_ycnt[32];
  __shared__ int s_resp[32];          // prefetched tables[b, v, x[b]]
  __shared__ float s_w1a[128], s_w1b[128], s_w1c[128], s_b1[128], s_w2[128];
  __shared__ float s_b2;
  __shared__ int s_nact, s_cnt, s_a, s_r;

  const int* tb = tables + (size_t)b * V * N;
  const int bo = base_obs[b];
  const int xb = x[b];

  // ---- phase 0: stage weights, prefetch responses, init, scan m0 ----
  if (tid < 128) s_w1a[tid] = W1[tid];
  else if (tid < 256) s_w1b[tid - 128] = W1[tid];
  else if (tid < 384) s_w1c[tid - 256] = W1[tid];
  else if (tid < 512) s_b1[tid - 384] = b1[tid - 384];
  else if (tid < 640) s_w2[tid - 512] = W2[tid - 512];
  else if (tid == 640) s_b2 = b2[0];
  else if (tid >= 704 && tid < 736) s_resp[tid - 704] = tb[(size_t)(tid - 704) * N + xb];
  if (tid < 32) s_used[tid] = 0;
  if (tid == 0) { s_nact = 0; s_cnt = 0; }
  __syncthreads();

  {
    const int4* tb4 = (const int4*)tb;
    for (int q = tid; q < (N >> 2); q += 1024) {
      int4 v4 = tb4[q];
      int base = q << 2;
      if (v4.x == bo) { int p = atomicAdd(&s_nact, 1); s_idx[0][p] = base; }
      if (v4.y == bo) { int p = atomicAdd(&s_nact, 1); s_idx[0][p] = base + 1; }
      if (v4.z == bo) { int p = atomicAdd(&s_nact, 1); s_idx[0][p] = base + 2; }
      if (v4.w == bo) { int p = atomicAdd(&s_nact, 1); s_idx[0][p] = base + 3; }
    }
  }
  __syncthreads();

  int cur = 0;

  // Fused (filter +) histogram pass. a_f<0: no filter (initial). Requires
  // s_cnt==0 on entry when a_f>=0 (zeroed in the argmax phase).
  auto fused_pass = [&](int a_f, int r_f, bool do_hist) {
    int nact = s_nact;
    if (a_f >= 0 && nact <= 1) {                 // trivial set: tid0 handles it
      if (tid == 0) {
        int nn = 0;
        if (nact == 1) {
          int i0 = s_idx[cur][0];
          nn = (tb[(size_t)a_f * N + i0] == r_f) ? 1 : 0;
        }
        s_nact = nn;
      }
      __syncthreads();
      return;
    }
    if (nact <= 256) {                           // single-round fused path
      if (do_hist) for (int i = tid; i < 32 * HPAD; i += 1024) s_hist[i] = 0;
      const int v = tid >> 5, g = tid & 31;
      const int* row = tb + (size_t)v * N;
      int labs[8];
      #pragma unroll
      for (int u = 0; u < 8; ++u) {
        int j = g + (u << 5);
        if (j < nact && (do_hist || (a_f >= 0 && v == a_f)))
          labs[u] = row[s_idx[cur][j]];
      }
      if (a_f >= 0 && v == a_f) {                // group a: survival + compaction
        #pragma unroll
        for (int u = 0; u < 8; ++u) {
          int j = g + (u << 5);
          if (j < nact) {
            int sv = (labs[u] == r_f);
            s_surv[j] = sv;
            if (sv) { int p = atomicAdd(&s_cnt, 1); s_idx[cur ^ 1][p] = s_idx[cur][j]; }
          }
        }
      }
      __syncthreads();
      int newn = (a_f >= 0) ? s_cnt : nact;
      if (do_hist && newn > 1) {                 // gated histogram atomics
        #pragma unroll
        for (int u = 0; u < 8; ++u) {
          int j = g + (u << 5);
          if (j < nact && (a_f < 0 || s_surv[j]))
            atomicAdd(&s_hist[v * HPAD + labs[u]], 1);
        }
      }
      if (a_f >= 0) { if (tid == 0) s_nact = s_cnt; cur ^= 1; }
      __syncthreads();
    } else {                                     // rare big-set fallback
      if (a_f >= 0) {
        for (int j = tid; j < nact; j += 1024) {
          int idx = s_idx[cur][j];
          if (tb[(size_t)a_f * N + idx] == r_f) {
            int p = atomicAdd(&s_cnt, 1); s_idx[cur ^ 1][p] = idx;
          }
        }
      }
      if (do_hist) for (int i = tid; i < 32 * HPAD; i += 1024) s_hist[i] = 0;
      __syncthreads();
      int nn = (a_f >= 0) ? s_cnt : nact;
      int nc = (a_f >= 0) ? (cur ^ 1) : cur;
      if (do_hist && nn > 1) {
        const int v = tid >> 5, g = tid & 31;
        const int* row = tb + (size_t)v * N;
        for (int base0 = 0; base0 < nn; base0 += 128) {
          int lab[4]; int valid = 0;
          #pragma unroll
          for (int u = 0; u < 4; ++u) {
            int j = base0 + u * 32 + g;
            if (j < nn) { lab[u] = row[s_idx[nc][j]]; valid |= (1 << u); }
          }
          #pragma unroll
          for (int u = 0; u < 4; ++u)
            if (valid & (1 << u)) atomicAdd(&s_hist[v * HPAD + lab[u]], 1);
        }
      }
      if (a_f >= 0) { if (tid == 0) s_nact = s_cnt; cur ^= 1; }
      __syncthreads();
    }
  };

  if (T > 0) fused_pass(-1, 0, true);            // histogram over m0

  int t = 0;
  for (; t < T; ++t) {
    // ---- fused features + MLP: 33 view-groups x 16 lanes ----
    if (tid < 528) {
      const int view = tid >> 4, l = tid & 15;
      const int nact = s_nact;
      const float total = (float)(nact > 1 ? nact : 1);
      float f0, f1, f2;
      if (view == 32) {
        bool closed = (total <= 1.0f);
        f0 = clip1000(closed ? 0.0f : 1000.0f);
        f1 = clip1000(total - 1.0f);
        f2 = clip1000(total);
      } else if (nact > 1) {
        long long sumsq = 0;
        #pragma unroll
        for (int o = l * 4; o < l * 4 + 4; ++o) {
          long long c = (long long)s_hist[view * HPAD + o];
          sumsq += c * c;
        }
        sumsq += __shfl_xor(sumsq, 1);
        sumsq += __shfl_xor(sumsq, 2);
        sumsq += __shfl_xor(sumsq, 4);
        sumsq += __shfl_xor(sumsq, 8);
        float es = (float)sumsq / total;
        float steps = (view == 0) ? 1000.0f : log2f(fmaxf(es, 1.0f));
        f0 = clip1000(steps); f1 = clip1000(es - 1.0f); f2 = clip1000(es);
      } else if (nact == 1) {   // closed-form, bit-identical to general path
        f0 = (view == 0) ? 1000.0f : 0.0f; f1 = 0.0f; f2 = 1.0f;
      } else {                  // nact == 0
        f0 = (view == 0) ? 1000.0f : 0.0f; f1 = -1.0f; f2 = 0.0f;
      }
      float zp = 0.0f;
      {
        #pragma clang fp contract(off)
        for (int k = l * 8; k < l * 8 + 8; ++k) {
          float pre = f0 * s_w1a[k] + f1 * s_w1b[k] + f2 * s_w1c[k] + s_b1[k];
          float e = erff(pre / (float)M_SQRT2);
          float hg = 0.5f * pre * (1.0f + e);   // exact GELU
          zp = zp + hg * s_w2[k];
        }
      }
      zp += __shfl_xor(zp, 1);
      zp += __shfl_xor(zp, 2);
      zp += __shfl_xor(zp, 4);
      zp += __shfl_xor(zp, 8);
      if (l == 0) s_z[view] = zp + s_b2;
    }
    __syncthreads();

    // ---- action selection (literal reference argmax chain) ----
    if (tid == 0) {
      int jstar = 0; float best = s_z[0];
      for (int i = 1; i < 33; ++i) {
        float v2 = s_z[i];
        if (v2 > best) { best = v2; jstar = i; }   // strict >: first max
      }
      int a = 0; float bv = -3.0e9f;
      for (int i = 0; i < 33; ++i) {
        float val = (i == jstar) ? 1.0f : 0.0f;    // one-hot z
        if (i == 0) val = NEGV;                    // forbid view 0
        else if (i < 32 && s_used[i]) val = NEGV;  // mask used views
        if (val > bv) { bv = val; a = i; }
      }
      int r = 0;
      if (a != 32) { s_used[a] = 1; r = s_resp[a]; }
      s_a = a; s_r = r; s_cnt = 0;                 // s_cnt pre-zeroed for fused pass
      out[b * T + t] = (float)a;
      out[B * T + b * T + t] = (float)r;
    }
    __syncthreads();

    const int a = s_a, r = s_r;
    if (a == 32) break;                            // stopped

    fused_pass(a, r, t < T - 1);                   // filter (+ next-step hist)
  }

  // stopped early: remaining actions are V (stop), responses 0
  if (t < T && tid == 0) {
    for (int tt = t + 1; tt < T; ++tt) {
      out[b * T + tt] = (float)V;
      out[B * T + b * T + tt] = 0.0f;
    }
  }

  // ---- y_logits: histogram sigma over surviving candidates ----
  if (tid < 32) s_ycnt[tid] = 0;
  __syncthreads();
  const int nfin = s_nact;
  const int* sg = sigma + (size_t)b * N;
  for (int j = tid; j < nfin; j += 1024) {
    atomicAdd(&s_ycnt[sg[s_idx[cur][j]]], 1);
  }
  __syncthreads();
  if (tid < 32) {
    float denom = (float)(nfin > 1 ? nfin : 1);
    float q = 1.0f / denom;
    int c = s_ycnt[tid];
    float p = 0.0f;
    for (int k = 0; k < c; ++k) p = p + q;  // fl-adds of equal values == scatter-add
    out[2 * B * T + b * 32 + tid] = logf(fmaxf(p, 1e-9f));
  }
}

extern "C" void kernel_launch(void* const* d_in, const int* in_sizes, int n_in,
                              void* d_out, int out_size, void* d_ws, size_t ws_size,
                              hipStream_t stream) {
  const int* tables   = (const int*)d_in[0];
  const int* sigma    = (const int*)d_in[1];
  const int* x        = (const int*)d_in[2];
  const int* base_obs = (const int*)d_in[3];
  const float* W1 = (const float*)d_in[4];
  const float* b1 = (const float*)d_in[5];
  const float* W2 = (const float*)d_in[6];
  const float* b2 = (const float*)d_in[7];
  const int* msteps = (const int*)d_in[8];
  float* out = (float*)d_out;

  const int B = in_sizes[2];
  const int N = in_sizes[1] / B;
  const int V = in_sizes[0] / (B * N);

  sim_kernel<<<dim3(B), dim3(1024), 0, stream>>>(
      tables, sigma, x, base_obs, W1, b1, W2, b2, msteps, out, B, V, N);
}

// Round 4
// 48.673 us; speedup vs baseline: 1.4149x; 1.4149x over previous
//
#include <hip/hip_runtime.h>
#include <math.h>

#define NEGV (-1.0e9f)
#define HP 65   // padded histogram row (kills stride-64 bank conflicts)

__device__ __forceinline__ float clip1000(float v) {
  return fminf(fmaxf(v, -1000.0f), 1000.0f);
}

__launch_bounds__(1024, 1)
__global__ void sim_kernel(const int* __restrict__ tables,
                           const int* __restrict__ sigma,
                           const int* __restrict__ x,
                           const int* __restrict__ base_obs,
                           const float* __restrict__ W1,
                           const float* __restrict__ b1,
                           const float* __restrict__ W2,
                           const float* __restrict__ b2,
                           const int* __restrict__ max_steps_p,
                           float* __restrict__ out,
                           int B, int V, int N)
{
  const int b = blockIdx.x;
  const int tid = threadIdx.x;
  const int T = max_steps_p[0];

  __shared__ unsigned short s_pos[8192];   // candidate positions (in-place compacted)
  __shared__ int s_gidx[8192];             // initial global indices
  __shared__ int s_lab[256 * 33];          // cached labels [pos][view], stride 33
  __shared__ int s_sig[256];               // cached sigma at candidates
  __shared__ int s_h[2][32 * HP];          // double-buffered histograms
  __shared__ int s_surv[256];              // per-chunk survival flags
  __shared__ float s_w1a[128], s_w1b[128], s_w1c[128], s_b1v[128], s_w2v[128];
  __shared__ float s_z[33];
  __shared__ int s_used[32];
  __shared__ int s_ycnt[32];
  __shared__ int s_resp[32];
  __shared__ float s_b2v;
  __shared__ int s_nact, s_cnt, s_a, s_r;

  const int* tb = tables + (size_t)b * V * N;
  const int* sg = sigma + (size_t)b * N;
  const int bo = base_obs[b];
  const int xb = x[b];

  // ---------------- phase A: weights, responses, zeros ----------------
  if (tid < 128) s_w1a[tid] = W1[tid];
  else if (tid < 256) s_w1b[tid - 128] = W1[tid];
  else if (tid < 384) s_w1c[tid - 256] = W1[tid];
  else if (tid < 512) s_b1v[tid - 384] = b1[tid - 384];
  else if (tid < 640) s_w2v[tid - 512] = W2[tid - 512];
  else if (tid == 640) s_b2v = b2[0];
  else if (tid >= 704 && tid < 736) s_resp[tid - 704] = tb[(size_t)(tid - 704) * N + xb];
  for (int i = tid; i < 2 * 32 * HP; i += 1024) ((int*)s_h)[i] = 0;
  if (tid < 32) { s_used[tid] = 0; s_ycnt[tid] = 0; }
  if (tid == 0) s_nact = 0;
  __syncthreads();

  // m0 scan -> s_gidx (coalesced int4)
  {
    const int4* tb4 = (const int4*)tb;
    for (int q = tid; q < (N >> 2); q += 1024) {
      int4 v4 = tb4[q]; int base = q << 2;
      if (v4.x == bo) { int p = atomicAdd(&s_nact, 1); s_gidx[p] = base; }
      if (v4.y == bo) { int p = atomicAdd(&s_nact, 1); s_gidx[p] = base + 1; }
      if (v4.z == bo) { int p = atomicAdd(&s_nact, 1); s_gidx[p] = base + 2; }
      if (v4.w == bo) { int p = atomicAdd(&s_nact, 1); s_gidx[p] = base + 3; }
    }
  }
  __syncthreads();

  const int nact0 = s_nact;
  const bool cached = (nact0 <= 256);
  const int v32 = tid >> 5, g32 = tid & 31;

  auto labelOf = [&](int pos, int vv) -> int {
    return cached ? s_lab[pos * 33 + vv] : tb[(size_t)vv * N + s_gidx[pos]];
  };

  // ---------------- phase B: one-shot gather + initial hist ----------------
  {
    const int* row = tb + (size_t)v32 * N;
    if (cached) {
      for (int j = g32; j < nact0; j += 32) {
        int lb = row[s_gidx[j]];
        s_lab[j * 33 + v32] = lb;
        atomicAdd(&s_h[0][v32 * HP + lb], 1);
      }
      for (int j = tid; j < nact0; j += 1024) s_sig[j] = sg[s_gidx[j]];
    } else {
      for (int j = g32; j < nact0; j += 32)
        atomicAdd(&s_h[0][v32 * HP + row[s_gidx[j]]], 1);
    }
    for (int j = tid; j < nact0; j += 1024) s_pos[j] = (unsigned short)j;
  }
  __syncthreads();

  // ---------------- heavy loop (nact > 2): all-LDS, 4 barriers/step ----------------
  int t = 0; bool stopped = false, tail = false; int hc = 0;
  while (t < T) {
    const int nact = s_nact;             // uniform (post-barrier)
    if (nact <= 2) { tail = true; break; }

    // PH1: features+MLP read s_h[hc]; idle threads zero s_h[hc^1]
    if (tid < 528) {
      const int view = tid >> 4, l = tid & 15;
      const float total = (float)nact;
      float f0, f1, f2;
      if (view == 32) {
        f0 = 1000.0f;                    // open (total>1): stop_steps=1000
        f1 = clip1000(total - 1.0f);
        f2 = clip1000(total);
      } else {
        long long sumsq = 0;
        #pragma unroll
        for (int o = l * 4; o < l * 4 + 4; ++o) {
          long long c = (long long)s_h[hc][view * HP + o];
          sumsq += c * c;
        }
        sumsq += __shfl_xor(sumsq, 1);
        sumsq += __shfl_xor(sumsq, 2);
        sumsq += __shfl_xor(sumsq, 4);
        sumsq += __shfl_xor(sumsq, 8);
        float es = (float)sumsq / total;
        float steps = (view == 0) ? 1000.0f : log2f(fmaxf(es, 1.0f));
        f0 = clip1000(steps); f1 = clip1000(es - 1.0f); f2 = clip1000(es);
      }
      float zp = 0.0f;
      {
        #pragma clang fp contract(off)
        for (int k = l * 8; k < l * 8 + 8; ++k) {
          float pre = f0 * s_w1a[k] + f1 * s_w1b[k] + f2 * s_w1c[k] + s_b1v[k];
          float e = erff(pre / (float)M_SQRT2);
          float hg = 0.5f * pre * (1.0f + e);   // exact GELU
          zp = zp + hg * s_w2v[k];
        }
      }
      zp += __shfl_xor(zp, 1);
      zp += __shfl_xor(zp, 2);
      zp += __shfl_xor(zp, 4);
      zp += __shfl_xor(zp, 8);
      if (l == 0) s_z[view] = zp + s_b2v;
    } else if (tid >= 544) {
      for (int i = tid - 544; i < 32 * HP; i += 480) s_h[hc ^ 1][i] = 0;
    }
    __syncthreads();

    // PH2: literal argmax chain
    if (tid == 0) {
      int jstar = 0; float best = s_z[0];
      for (int i = 1; i < 33; ++i) { float zz = s_z[i]; if (zz > best) { best = zz; jstar = i; } }
      int a = 0; float bv = -3.0e9f;
      for (int i = 0; i < 33; ++i) {
        float val = (i == jstar) ? 1.0f : 0.0f;
        if (i == 0) val = NEGV;
        else if (i < 32 && s_used[i]) val = NEGV;
        if (val > bv) { bv = val; a = i; }
      }
      int r = 0;
      if (a != 32) { s_used[a] = 1; r = s_resp[a]; }
      s_a = a; s_r = r; s_cnt = 0;
      out[b * T + t] = (float)a;
      out[(size_t)B * T + b * T + t] = (float)r;
    }
    __syncthreads();

    const int a = s_a, r = s_r;
    if (a == 32) { stopped = true; break; }

    // PH3/PH4: fused filter + next-hist, chunks of 256, in-place compaction
    for (int c0 = 0; c0 < nact; c0 += 256) {
      int labs[8], poss[8];
      #pragma unroll
      for (int u = 0; u < 8; ++u) {
        int j = c0 + g32 + (u << 5);
        if (j < nact) { poss[u] = s_pos[j]; labs[u] = labelOf(poss[u], v32); }
      }
      if (v32 == a) {
        #pragma unroll
        for (int u = 0; u < 8; ++u) {
          int j = c0 + g32 + (u << 5);
          if (j < nact) s_surv[j - c0] = (labs[u] == r);
        }
      }
      __syncthreads();
      if (v32 == a) {
        #pragma unroll
        for (int u = 0; u < 8; ++u) {
          int j = c0 + g32 + (u << 5);
          if (j < nact && labs[u] == r) {
            int p = atomicAdd(&s_cnt, 1);
            s_pos[p] = (unsigned short)poss[u];   // safe: p < c0+256 <= next chunk start
          }
        }
      }
      #pragma unroll
      for (int u = 0; u < 8; ++u) {
        int j = c0 + g32 + (u << 5);
        if (j < nact && s_surv[j - c0]) atomicAdd(&s_h[hc ^ 1][v32 * HP + labs[u]], 1);
      }
      __syncthreads();
    }
    if (tid == 0) s_nact = s_cnt;
    hc ^= 1;
    ++t;
    __syncthreads();
  }

  if (stopped && tid == 0) {
    for (int tt = t + 1; tt < T; ++tt) {
      out[b * T + tt] = (float)V;
      out[(size_t)B * T + b * T + tt] = 0.0f;
    }
  }

  // ---------------- single-wave serial tail (nact <= 2), zero barriers ----------------
  if (tail) {
    if (tid < 64) {
      const int lane = tid;
      int nact = s_nact;
      int p0 = (nact >= 1) ? (int)s_pos[0] : 0;
      int p1 = (nact == 2) ? (int)s_pos[1] : 0;
      unsigned usedmask;
      { bool ub = (lane < 32) && (s_used[lane] != 0);
        usedmask = (unsigned)__ballot(ub); }

      auto mlp2 = [&](float f0, float f1, float f2) -> float {
        float zp = 0.0f;
        {
          #pragma clang fp contract(off)
          for (int k = lane * 2; k < lane * 2 + 2; ++k) {
            float pre = f0 * s_w1a[k] + f1 * s_w1b[k] + f2 * s_w1c[k] + s_b1v[k];
            float e = erff(pre / (float)M_SQRT2);
            float hg = 0.5f * pre * (1.0f + e);
            zp = zp + hg * s_w2v[k];
          }
        }
        zp += __shfl_xor(zp, 1);  zp += __shfl_xor(zp, 2);
        zp += __shfl_xor(zp, 4);  zp += __shfl_xor(zp, 8);
        zp += __shfl_xor(zp, 16); zp += __shfl_xor(zp, 32);
        return zp + s_b2v;
      };

      float zE1 = 0.f, zE2 = 0.f, zE3 = 0.f, zE4 = 0.f;
      unsigned esmask = 0; bool zvalid = false;
      for (; t < T; ++t) {
        if (!zvalid) {
          if (nact == 2) {
            int l0 = (lane < 32) ? labelOf(p0, lane) : 0;
            int l1 = (lane < 32) ? labelOf(p1, lane) : 0;
            esmask = (unsigned)__ballot(lane < 32 && (l0 == l1));
            zE1 = mlp2(1.0f, 1.0f, 2.0f);        // view, es=2: [log2(2),1,2]
            zE2 = mlp2(0.0f, 0.0f, 1.0f);        // view, es=1
            zE3 = mlp2(1000.0f, 0.0f, 1.0f);     // view0, es0=1
            zE4 = mlp2(1000.0f, 1.0f, 2.0f);     // view0 es0=2, and stop(open,total=2)
          } else if (nact == 1) {
            zE2 = mlp2(0.0f, 0.0f, 1.0f);        // views; stop(closed) identical features
            zE3 = mlp2(1000.0f, 0.0f, 1.0f);     // view0
          } else {                               // nact == 0
            zE2 = mlp2(0.0f, -1.0f, 0.0f);       // views (es=0)
            zE3 = mlp2(1000.0f, -1.0f, 0.0f);    // view0
            zE4 = mlp2(0.0f, 0.0f, 1.0f);        // stop (closed, total=1)
          }
          zvalid = true;
        }
        // argmax over z (first-max), then one-hot/NEG chain — uniform on all lanes
        int jstar; float best;
        if (nact == 2) {
          best = (esmask & 1u) ? zE4 : zE3; jstar = 0;
          for (int i = 1; i < 32; ++i) {
            float zz = ((esmask >> i) & 1u) ? zE1 : zE2;
            if (zz > best) { best = zz; jstar = i; }
          }
          if (zE4 > best) { best = zE4; jstar = 32; }
        } else if (nact == 1) {
          best = zE3; jstar = 0;
          if (zE2 > best) { best = zE2; jstar = 1; }   // views & stop all == zE2
        } else {
          best = zE3; jstar = 0;
          if (zE2 > best) { best = zE2; jstar = 1; }
          if (zE4 > best) { best = zE4; jstar = 32; }
        }
        int a = 0; float bv = -3.0e9f;
        for (int i = 0; i < 33; ++i) {
          float val = (i == jstar) ? 1.0f : 0.0f;
          if (i == 0) val = NEGV;
          else if (i < 32 && ((usedmask >> i) & 1u)) val = NEGV;
          if (val > bv) { bv = val; a = i; }
        }
        if (a == 32) {
          if (lane == 0) {
            for (int tt = t; tt < T; ++tt) {
              out[b * T + tt] = (float)V;
              out[(size_t)B * T + b * T + tt] = 0.0f;
            }
          }
          break;
        }
        usedmask |= (1u << a);
        int r = s_resp[a];
        if (lane == 0) {
          out[b * T + t] = (float)a;
          out[(size_t)B * T + b * T + t] = (float)r;
        }
        // filter (labels from LDS cache; uniform loads)
        if (nact == 2) {
          bool k0 = (labelOf(p0, a) == r);
          bool k1 = (labelOf(p1, a) == r);
          if (k0 && k1) { /* pair unchanged: z cache stays valid */ }
          else if (k0) { nact = 1; zvalid = false; }
          else if (k1) { nact = 1; p0 = p1; zvalid = false; }
          else { nact = 0; zvalid = false; }
        } else if (nact == 1) {
          if (labelOf(p0, a) != r) { nact = 0; zvalid = false; }
        }
      }
      if (lane == 0) {
        s_nact = nact;
        if (nact >= 1) s_pos[0] = (unsigned short)p0;
      }
    }
    __syncthreads();
  }

  // ---------------- epilogue: y_logits over survivors ----------------
  const int nfin = s_nact;
  for (int j = tid; j < nfin; j += 1024) {
    int pos = s_pos[j];
    int sv = cached ? s_sig[pos] : sg[s_gidx[pos]];
    atomicAdd(&s_ycnt[sv], 1);
  }
  __syncthreads();
  if (tid < 32) {
    float denom = (float)(nfin > 1 ? nfin : 1);
    float q = 1.0f / denom;
    int c = s_ycnt[tid];
    float p = 0.0f;
    for (int k = 0; k < c; ++k) p = p + q;  // fl-adds of equal values == scatter-add
    out[(size_t)2 * B * T + b * 32 + tid] = logf(fmaxf(p, 1e-9f));
  }
}

extern "C" void kernel_launch(void* const* d_in, const int* in_sizes, int n_in,
                              void* d_out, int out_size, void* d_ws, size_t ws_size,
                              hipStream_t stream) {
  const int* tables   = (const int*)d_in[0];
  const int* sigma    = (const int*)d_in[1];
  const int* x        = (const int*)d_in[2];
  const int* base_obs = (const int*)d_in[3];
  const float* W1 = (const float*)d_in[4];
  const float* b1 = (const float*)d_in[5];
  const float* W2 = (const float*)d_in[6];
  const float* b2 = (const float*)d_in[7];
  const int* msteps = (const int*)d_in[8];
  float* out = (float*)d_out;

  const int B = in_sizes[2];
  const int N = in_sizes[1] / B;
  const int V = in_sizes[0] / (B * N);

  sim_kernel<<<dim3(B), dim3(1024), 0, stream>>>(
      tables, sigma, x, base_obs, W1, b1, W2, b2, msteps, out, B, V, N);
}